// Round 6
// baseline (1338.666 us; speedup 1.0000x reference)
//
#include <hip/hip_runtime.h>
#include <stdint.h>

#define T_LEN 4096
#define NHID  128

typedef float    f32x4 __attribute__((ext_vector_type(4)));
typedef _Float16 f16x4 __attribute__((ext_vector_type(4)));
typedef _Float16 f16x8 __attribute__((ext_vector_type(8)));
typedef __fp16   h16x2 __attribute__((ext_vector_type(2)));
typedef uint32_t u32x2 __attribute__((ext_vector_type(2)));
typedef uint32_t u32x4 __attribute__((ext_vector_type(4)));

struct P2 { h16x2 p0, p1; };
struct P4 { h16x2 p0, p1, p2, p3; };
struct U22 { u32x2 a, b; };

static __device__ __forceinline__ f16x4 cvt_f16x4(f32x4 v) {
    P2 p;
    p.p0 = __builtin_amdgcn_cvt_pkrtz(v.x, v.y);
    p.p1 = __builtin_amdgcn_cvt_pkrtz(v.z, v.w);
    return __builtin_bit_cast(f16x4, p);
}
static __device__ __forceinline__ f16x8 cvt_f16x8(f32x4 a, f32x4 b) {
    P4 p;
    p.p0 = __builtin_amdgcn_cvt_pkrtz(a.x, a.y);
    p.p1 = __builtin_amdgcn_cvt_pkrtz(a.z, a.w);
    p.p2 = __builtin_amdgcn_cvt_pkrtz(b.x, b.y);
    p.p3 = __builtin_amdgcn_cvt_pkrtz(b.z, b.w);
    return __builtin_bit_cast(f16x8, p);
}
static __device__ __forceinline__ f32x4 relu4(f32x4 v) {
    v.x = fmaxf(v.x, 0.f); v.y = fmaxf(v.y, 0.f);
    v.z = fmaxf(v.z, 0.f); v.w = fmaxf(v.w, 0.f);
    return v;
}
// pack f32x4 -> 4 f16 (RTZ) then relu in f16 (identical result to relu-then-pack)
static __device__ __forceinline__ u32x2 relu_pk(f32x4 v) {
    P2 p;
    p.p0 = __builtin_amdgcn_cvt_pkrtz(v.x, v.y);
    p.p1 = __builtin_amdgcn_cvt_pkrtz(v.z, v.w);
    f16x4 h = __builtin_bit_cast(f16x4, p);
    const f16x4 z = {};
    h = __builtin_elementwise_max(h, z);   // 2x v_pk_max_f16
    return __builtin_bit_cast(u32x2, h);
}
static __device__ __forceinline__ f32x4 unpk4(u32x2 q) {
    f16x4 h = __builtin_bit_cast(f16x4, q);
    f32x4 r = { (float)h.x, (float)h.y, (float)h.z, (float)h.w };
    return r;
}
#define MFMA32(a, b, c) __builtin_amdgcn_mfma_f32_16x16x32_f16((a), (b), (c), 0, 0, 0)

// LDS-only barrier: drains LDS ops, leaves global (vmcnt) traffic in flight.
#define LDS_BARRIER()  asm volatile("s_waitcnt lgkmcnt(0)\n\ts_barrier" ::: "memory")

// Layouts (per batch group g; lane l=(u<<4)|c, batch=16g+c):
//   phiC (C-frag / h / xp storage): unit(m,u,i) = 16m + 4u + i
//   phiB (W1h K-axis gather):  unit(kt,u,j) = 64*(j>>2) + 16kt + 4u + (j&3)
// B-frag[kt] of step t+1 == concat(pk[kt], pk[kt+4]) of step t's packed C
// output. Wave w owns m = {w, w+4}: bf[w] is FULLY LOCAL (register concat);
// 3 frags/step cross waves via LDS. The stored q-th u32x4 {pk[q],pk[q+4]}
// is ALSO verbatim a K=32 B-frag (phiB with kt=q) -> out_kernel uses MFMA32.
//
// xp (packed f16, in d_out): xp[(g*T+t)*1024 + q*256 + 4l + 0..3] (u32)
//   q-th u32x4 = { pk[q], pk[q+4] }
// hg (packed f16, in d_ws):  hg[(g*T+t)*1024 + q*256 + 4l + 0..3] (u32)
//   q-th u32x4 = { pk[q], pk[q+4] }   (h_{t+1} at index t)

// -------------------------------------------------------------------------
// Kernel 0: xp = input . W1x^T + b1 (K=32 MFMA), packed f16, paired layout.
// Grid 1024 = g*256 + tc, block 64, 16 t per block.
// -------------------------------------------------------------------------
__global__ __launch_bounds__(64, 2)
void xproj_kernel(const float* __restrict__ input, const float* __restrict__ W1,
                  const float* __restrict__ b1, uint32_t* __restrict__ xp) {
    const int bid = blockIdx.x;
    const int g   = bid >> 8;          // 0..3
    const int tc  = bid & 255;         // 0..255
    const int l   = threadIdx.x;
    const int c   = l & 15, u = l >> 4;

    // A-fragments of W1x (cols 128..255): A[m=c][k=32j+8u+0..7]
    f16x8 wa[8][4];
#pragma unroll
    for (int m = 0; m < 8; ++m) {
        const float* wr = W1 + (16 * m + c) * 256 + 128 + 8 * u;
#pragma unroll
        for (int j = 0; j < 4; ++j)
            wa[m][j] = cvt_f16x8(*(const f32x4*)(wr + 32 * j),
                                 *(const f32x4*)(wr + 32 * j + 4));
    }
    f32x4 bi[8];
#pragma unroll
    for (int m = 0; m < 8; ++m) bi[m] = *(const f32x4*)(b1 + 16 * m + 4 * u);

    const int t0 = tc * 16;
    const float* ip0 = input + (size_t)(16 * g + c) * T_LEN * NHID + 8 * u;
    uint32_t* xp0 = xp + ((size_t)g * T_LEN) * 1024 + 4 * l;
#pragma unroll 1
    for (int tt = 0; tt < 16; ++tt) {
        const int t = t0 + tt;
        const float* ip = ip0 + (size_t)t * NHID;
        f16x8 xb[4];
#pragma unroll
        for (int j = 0; j < 4; ++j)
            xb[j] = cvt_f16x8(*(const f32x4*)(ip + 32 * j),
                              *(const f32x4*)(ip + 32 * j + 4));
        u32x2 pk[8];
#pragma unroll
        for (int m = 0; m < 8; ++m) {
            f32x4 a = bi[m];
#pragma unroll
            for (int j = 0; j < 4; ++j) a = MFMA32(wa[m][j], xb[j], a);
            pk[m] = __builtin_bit_cast(u32x2, cvt_f16x4(a));
        }
        uint32_t* xpt = xp0 + (size_t)t * 1024;
#pragma unroll
        for (int q = 0; q < 4; ++q) {
            U22 qq = { pk[q], pk[q + 4] };   // paired layout {m=q, m=q+4}
            *(u32x4*)(xpt + q * 256) = __builtin_bit_cast(u32x4, qq);
        }
    }
}

// -------------------------------------------------------------------------
// Kernel 1: recurrence. Grid 4 (g), block 256 = 4 symmetric compute waves
// (NO drain wave: narrower barrier, no SIMD-0 contention, no extra LDS
// port traffic).
//   Wave w (SIMD w) owns m = {w, w+4}. Per step: 3 ds_read_b128 (remote
//   frags), 4 accumulator chains of depth 2 merged by v_add, pack, 1
//   ds_write_b128 (publish), next step's 2 LOCAL head MFMAs issued
//   PRE-barrier (absorb barrier-wait slack), 1 xp ring load (depth 8).
//   h->HBM: each wave stores its own u32x4, DELAYED 4 steps through an
//   8-slot register ring (pkv). Slot written at t is read (stored) at
//   t+4 and redefined at t+8 -> store-data WAR distance ~1500 cyc, no
//   vmcnt stall; slots provably live -> distinct VGPRs.
// -------------------------------------------------------------------------
__global__ __launch_bounds__(256, 1)
void rec_kernel(const uint32_t* __restrict__ xp, const float* __restrict__ W1,
                uint32_t* __restrict__ hg) {
    const int g = blockIdx.x;
    const int w = threadIdx.x >> 6;   // 0..3
    const int l = threadIdx.x & 63;
    const int c = l & 15, u = l >> 4;

    __shared__ uint32_t hbuf[4][1024];   // 4-slot ring, 16 KB

    // h_0 = 0: zero slot 0
    for (int i = threadIdx.x; i < 1024; i += 256) hbuf[0][i] = 0;
    __syncthreads();

    // A-frags for m = w (e=0) and m = w+4 (e=1), phiB K-gather:
    //   waH[e][kt] elem j = W1h[16m+c][ 64*(j>>2) + 16kt + 4u + (j&3) ]
    f16x8 waH[2][4];
#pragma unroll
    for (int e = 0; e < 2; ++e) {
        const float* wr = W1 + (16 * (w + 4 * e) + c) * 256;  // cols 0..127
#pragma unroll
        for (int kt = 0; kt < 4; ++kt)
            waH[e][kt] = cvt_f16x8(*(const f32x4*)(wr + 16 * kt + 4 * u),
                                   *(const f32x4*)(wr + 64 + 16 * kt + 4 * u));
    }

    const uint32_t* xpl = xp + ((size_t)g * T_LEN) * 1024 + w * 256 + 4 * l;
    uint32_t*       hgp = hg + ((size_t)g * T_LEN) * 1024 + w * 256 + 4 * l;

    // xp prefetch ring, depth 8 (one b128 per step)
    u32x4 xr[8];
#pragma unroll
    for (int p = 0; p < 8; ++p)
        xr[p] = *(const u32x4*)(xpl + (size_t)p * 1024);

    // own B-frag bf[w] = {pk[w], pk[w+4]}; h_0 = 0
    f16x8 own;
    {
        const u32x4 z = {0, 0, 0, 0};
        own = __builtin_bit_cast(f16x8, z);
    }
    // loop invariant at entry of iter t: a0a/a1a = local heads for step t,
    // xf0/xf1 = unpacked xp of step t+1, own = h_t own-frag.
    f32x4 xf0, xf1, a0a, a1a;
    {
        U22 xq = __builtin_bit_cast(U22, xr[0]);
        xf0 = unpk4(xq.a);
        xf1 = unpk4(xq.b);
        a0a = MFMA32(waH[0][w], own, xf0);   // B=0 -> passes xf through
        a1a = MFMA32(waH[1][w], own, xf1);
        U22 xn = __builtin_bit_cast(U22, xr[1]);
        xf0 = unpk4(xn.a);
        xf1 = unpk4(xn.b);
    }
    u32x2 pkv[8][2];                         // 4-step-delayed store ring
    const f32x4 zf = { 0.f, 0.f, 0.f, 0.f };
    const int k1 = (w + 1) & 3, k2 = (w + 2) & 3, k3 = (w + 3) & 3;

#pragma unroll 1
    for (int t8 = 0; t8 < T_LEN; t8 += 8) {
#pragma unroll
        for (int p = 0; p < 8; ++p) {
            const int t = t8 + p;
            const uint32_t* rb = &hbuf[p & 3][0];   // slot t&3 = h_t
            // remote frags: issue at barrier+0, land under store/refill/MFMA
            u32x4 r1 = *(const u32x4*)&rb[k1 * 256 + 4 * l];
            u32x4 r2 = *(const u32x4*)&rb[k2 * 256 + 4 * l];
            u32x4 r3 = *(const u32x4*)&rb[k3 * 256 + 4 * l];
            // delayed h store: slot (t-4)&7 holds h_{t-3} -> hg[t-4]
            if (t >= 4) {
                U22 sq = { pkv[(p + 4) & 7][0], pkv[(p + 4) & 7][1] };
                *(u32x4*)(hgp + (size_t)(t - 4) * 1024) =
                    __builtin_bit_cast(u32x4, sq);
            }
            // ring refill for t+8 (clamped tail; dummies unused)
            int tn = t + 8; if (tn > T_LEN - 1) tn = T_LEN - 1;
            xr[p] = *(const u32x4*)(xpl + (size_t)tn * 1024);
            // 4 chains of depth 2 (heads a0a/a1a computed pre-barrier)
            f16x8 b1 = __builtin_bit_cast(f16x8, r1);
            f32x4 a0b = MFMA32(waH[0][k1], b1, zf);
            f32x4 a1b = MFMA32(waH[1][k1], b1, zf);
            f16x8 b2 = __builtin_bit_cast(f16x8, r2);
            a0a = MFMA32(waH[0][k2], b2, a0a);
            a1a = MFMA32(waH[1][k2], b2, a1a);
            f16x8 b3 = __builtin_bit_cast(f16x8, r3);
            a0b = MFMA32(waH[0][k3], b3, a0b);
            a1b = MFMA32(waH[1][k3], b3, a1b);
            // merge, pack h_{t+1}; own bf for t+1 is the register concat
            u32x2 p0 = relu_pk(a0a + a0b);
            u32x2 p1 = relu_pk(a1a + a1b);
            pkv[p & 7][0] = p0;              // read by store at iter t+4
            pkv[p & 7][1] = p1;
            U22 oq = { p0, p1 };
            own = __builtin_bit_cast(f16x8, oq);
            // publish own frag into slot (t+1)&3
            *(u32x4*)&hbuf[(p + 1) & 3][w * 256 + 4 * l] =
                __builtin_bit_cast(u32x4, oq);
            // next step's LOCAL heads: register-only, issued PRE-barrier to
            // absorb barrier-wait slack
            a0a = MFMA32(waH[0][w], own, xf0);
            a1a = MFMA32(waH[1][w], own, xf1);
            // unpack xp for step t+2 (pre-barrier tail filler)
            {
                U22 xq = __builtin_bit_cast(U22, xr[(p + 2) & 7]);
                xf0 = unpk4(xq.a);
                xf1 = unpk4(xq.b);
            }
            LDS_BARRIER();
        }
    }
    // epilogue: stores for the last 4 steps (h_{T-3}..h_T -> hg[T-4..T-1])
#pragma unroll
    for (int d = 0; d < 4; ++d) {
        U22 sq = { pkv[(T_LEN - 4 + d) & 7][0], pkv[(T_LEN - 4 + d) & 7][1] };
        *(u32x4*)(hgp + (size_t)(T_LEN - 4 + d) * 1024) =
            __builtin_bit_cast(u32x4, sq);
    }
}

// -------------------------------------------------------------------------
// Kernel 2: out[b,t,:] = relu(W2 . h_{t+1} + b2), now K=32 MFMA: the stored
// q-th u32x4 of hg is verbatim a 16x16x32 B-frag (phiB with kt=q), so loads
// become 4 fully-coalesced u32x4 per t (was 8 half-width strided u32x2) and
// MFMA count halves. A-frags of W2 use the same phiB two-load gather.
// Grid 2048 = g*512 + tc, block 64, 8 t per block.
// -------------------------------------------------------------------------
__global__ __launch_bounds__(64, 2)
void out_kernel(const uint32_t* __restrict__ hg, const float* __restrict__ W2,
                const float* __restrict__ b2, float* __restrict__ out) {
    const int bid = blockIdx.x;
    const int g   = bid >> 9;
    const int tc  = bid & 511;
    const int l   = threadIdx.x;
    const int c   = l & 15, u = l >> 4;

    // A[m][q] elem j = W2[16m+c][ 64*(j>>2) + 16q + 4u + (j&3) ]
    f16x8 wa[8][4];
#pragma unroll
    for (int m = 0; m < 8; ++m) {
        const float* wr = W2 + (16 * m + c) * 128;
#pragma unroll
        for (int q = 0; q < 4; ++q)
            wa[m][q] = cvt_f16x8(*(const f32x4*)(wr + 16 * q + 4 * u),
                                 *(const f32x4*)(wr + 64 + 16 * q + 4 * u));
    }
    f32x4 bi[8];
#pragma unroll
    for (int m = 0; m < 8; ++m) bi[m] = *(const f32x4*)(b2 + 16 * m + 4 * u);

    const int t0 = tc * 8;
    const uint32_t* hg0 = hg + ((size_t)g * T_LEN) * 1024 + 4 * l;
    float* op0 = out + (size_t)(16 * g + c) * T_LEN * NHID + 4 * u;
#pragma unroll 1
    for (int tt = 0; tt < 8; ++tt) {
        const int t = t0 + tt;
        const uint32_t* hp = hg0 + (size_t)t * 1024;
        f16x8 hb[4];
#pragma unroll
        for (int q = 0; q < 4; ++q)
            hb[q] = __builtin_bit_cast(f16x8, *(const u32x4*)(hp + q * 256));
        f32x4 acc[8];
#pragma unroll
        for (int m = 0; m < 8; ++m) {
            f32x4 a = bi[m];
#pragma unroll
            for (int q = 0; q < 4; ++q) a = MFMA32(wa[m][q], hb[q], a);
            acc[m] = relu4(a);
        }
        float* op = op0 + (size_t)t * NHID;
#pragma unroll
        for (int m = 0; m < 8; ++m) *(f32x4*)(op + 16 * m) = acc[m];
    }
}

// -------------------------------------------------------------------------
extern "C" void kernel_launch(void* const* d_in, const int* in_sizes, int n_in,
                              void* d_out, int out_size, void* d_ws, size_t ws_size,
                              hipStream_t stream) {
    const float* input = (const float*)d_in[0];  // (64, 4096, 128) f32
    const float* W1    = (const float*)d_in[1];  // (128, 256) f32
    const float* b1    = (const float*)d_in[2];  // (128,) f32
    const float* W2    = (const float*)d_in[3];  // (128, 128) f32
    const float* b2    = (const float*)d_in[4];  // (128,) f32
    float*    out = (float*)d_out;
    uint32_t* xpb = (uint32_t*)d_out;            // xp scratch (64 MiB, f16-
                                                 // packed) in d_out; fully
                                                 // consumed by rec before
                                                 // out_kernel overwrites
    uint32_t* hgb = (uint32_t*)d_ws;             // h stream: 64 MiB in d_ws

    xproj_kernel<<<1024, 64, 0, stream>>>(input, W1, b1, xpb);
    rec_kernel  <<<4,   256, 0, stream>>>(xpb, W1, hgb);
    out_kernel  <<<2048, 64, 0, stream>>>(hgb, W2, b2, out);
}

// Round 8
// 1248.989 us; speedup vs baseline: 1.0718x; 1.0718x over previous
//
#include <hip/hip_runtime.h>
#include <stdint.h>

#define T_LEN 4096
#define NHID  128

typedef float    f32x4 __attribute__((ext_vector_type(4)));
typedef _Float16 f16x4 __attribute__((ext_vector_type(4)));
typedef _Float16 f16x8 __attribute__((ext_vector_type(8)));
typedef __fp16   h16x2 __attribute__((ext_vector_type(2)));
typedef uint32_t u32x2 __attribute__((ext_vector_type(2)));
typedef uint32_t u32x4 __attribute__((ext_vector_type(4)));

struct P2 { h16x2 p0, p1; };
struct P4 { h16x2 p0, p1, p2, p3; };
struct U22 { u32x2 a, b; };

static __device__ __forceinline__ f16x4 cvt_f16x4(f32x4 v) {
    P2 p;
    p.p0 = __builtin_amdgcn_cvt_pkrtz(v.x, v.y);
    p.p1 = __builtin_amdgcn_cvt_pkrtz(v.z, v.w);
    return __builtin_bit_cast(f16x4, p);
}
static __device__ __forceinline__ f16x8 cvt_f16x8(f32x4 a, f32x4 b) {
    P4 p;
    p.p0 = __builtin_amdgcn_cvt_pkrtz(a.x, a.y);
    p.p1 = __builtin_amdgcn_cvt_pkrtz(a.z, a.w);
    p.p2 = __builtin_amdgcn_cvt_pkrtz(b.x, b.y);
    p.p3 = __builtin_amdgcn_cvt_pkrtz(b.z, b.w);
    return __builtin_bit_cast(f16x8, p);
}
static __device__ __forceinline__ f32x4 relu4(f32x4 v) {
    v.x = fmaxf(v.x, 0.f); v.y = fmaxf(v.y, 0.f);
    v.z = fmaxf(v.z, 0.f); v.w = fmaxf(v.w, 0.f);
    return v;
}
// pack f32x4 -> 4 f16 (RTZ) then relu in f16 (identical result to relu-then-pack)
static __device__ __forceinline__ u32x2 relu_pk(f32x4 v) {
    P2 p;
    p.p0 = __builtin_amdgcn_cvt_pkrtz(v.x, v.y);
    p.p1 = __builtin_amdgcn_cvt_pkrtz(v.z, v.w);
    f16x4 h = __builtin_bit_cast(f16x4, p);
    const f16x4 z = {};
    h = __builtin_elementwise_max(h, z);   // 2x v_pk_max_f16
    return __builtin_bit_cast(u32x2, h);
}
static __device__ __forceinline__ f32x4 unpk4(u32x2 q) {
    f16x4 h = __builtin_bit_cast(f16x4, q);
    f32x4 r = { (float)h.x, (float)h.y, (float)h.z, (float)h.w };
    return r;
}
#define MFMA32(a, b, c) __builtin_amdgcn_mfma_f32_16x16x32_f16((a), (b), (c), 0, 0, 0)

// LDS-only barrier, NO "memory" clobber. An asm with a "memory" clobber may
// touch any memory, so the waitcnt pass drains vmcnt(0) (all in-flight loads
// AND stores) before it -- a full HBM round-trip per step, the very stall
// this macro exists to avoid (diagnosed R6: step time tracked store-ack).
// Pattern proven in learn_hip m201: naked waitcnt asm + raw s_barrier keeps
// global traffic in flight. sched_barrier(0) on both sides pins the publish
// ds_write before the waitcnt and the next step's ds_reads after the
// barrier (rule #18: hipcc otherwise hoists across naked waitcnt asm).
#define LDS_BARRIER()                                   \
    do {                                                \
        __builtin_amdgcn_sched_barrier(0);              \
        asm volatile("s_waitcnt lgkmcnt(0)");           \
        __builtin_amdgcn_s_barrier();                   \
        __builtin_amdgcn_sched_barrier(0);              \
    } while (0)

// Layouts (per batch group g; lane l=(u<<4)|c, batch=16g+c):
//   phiC (C-frag / h / xp storage): unit(m,u,i) = 16m + 4u + i
//   phiB (W1h K-axis gather):  unit(kt,u,j) = 64*(j>>2) + 16kt + 4u + (j&3)
// B-frag[kt] of step t+1 == concat(pk[kt], pk[kt+4]) of step t's packed C
// output. Wave w owns m = {w, w+4}: bf[w] is FULLY LOCAL (register concat);
// 3 frags/step cross waves via LDS. The stored q-th u32x4 {pk[q],pk[q+4]}
// is ALSO verbatim a K=32 B-frag (phiB with kt=q) -> out_kernel uses MFMA32.
//
// xp (packed f16, in d_out): xp[(g*T+t)*1024 + q*256 + 4l + 0..3] (u32)
//   q-th u32x4 = { pk[q], pk[q+4] }
// hg (packed f16, in d_ws):  hg[(g*T+t)*1024 + q*256 + 4l + 0..3] (u32)
//   q-th u32x4 = { pk[q], pk[q+4] }   (h_{t+1} at index t)

// -------------------------------------------------------------------------
// Kernel 0: xp = input . W1x^T + b1 (K=32 MFMA), packed f16, paired layout.
// Grid 1024 = g*256 + tc, block 64, 16 t per block.
// -------------------------------------------------------------------------
__global__ __launch_bounds__(64, 2)
void xproj_kernel(const float* __restrict__ input, const float* __restrict__ W1,
                  const float* __restrict__ b1, uint32_t* __restrict__ xp) {
    const int bid = blockIdx.x;
    const int g   = bid >> 8;          // 0..3
    const int tc  = bid & 255;         // 0..255
    const int l   = threadIdx.x;
    const int c   = l & 15, u = l >> 4;

    // A-fragments of W1x (cols 128..255): A[m=c][k=32j+8u+0..7]
    f16x8 wa[8][4];
#pragma unroll
    for (int m = 0; m < 8; ++m) {
        const float* wr = W1 + (16 * m + c) * 256 + 128 + 8 * u;
#pragma unroll
        for (int j = 0; j < 4; ++j)
            wa[m][j] = cvt_f16x8(*(const f32x4*)(wr + 32 * j),
                                 *(const f32x4*)(wr + 32 * j + 4));
    }
    f32x4 bi[8];
#pragma unroll
    for (int m = 0; m < 8; ++m) bi[m] = *(const f32x4*)(b1 + 16 * m + 4 * u);

    const int t0 = tc * 16;
    const float* ip0 = input + (size_t)(16 * g + c) * T_LEN * NHID + 8 * u;
    uint32_t* xp0 = xp + ((size_t)g * T_LEN) * 1024 + 4 * l;
#pragma unroll 1
    for (int tt = 0; tt < 16; ++tt) {
        const int t = t0 + tt;
        const float* ip = ip0 + (size_t)t * NHID;
        f16x8 xb[4];
#pragma unroll
        for (int j = 0; j < 4; ++j)
            xb[j] = cvt_f16x8(*(const f32x4*)(ip + 32 * j),
                              *(const f32x4*)(ip + 32 * j + 4));
        u32x2 pk[8];
#pragma unroll
        for (int m = 0; m < 8; ++m) {
            f32x4 a = bi[m];
#pragma unroll
            for (int j = 0; j < 4; ++j) a = MFMA32(wa[m][j], xb[j], a);
            pk[m] = __builtin_bit_cast(u32x2, cvt_f16x4(a));
        }
        uint32_t* xpt = xp0 + (size_t)t * 1024;
#pragma unroll
        for (int q = 0; q < 4; ++q) {
            U22 qq = { pk[q], pk[q + 4] };   // paired layout {m=q, m=q+4}
            *(u32x4*)(xpt + q * 256) = __builtin_bit_cast(u32x4, qq);
        }
    }
}

// -------------------------------------------------------------------------
// Kernel 1: recurrence. Grid 4 (g), block 256 = 4 symmetric compute waves.
//   Wave w (SIMD w) owns m = {w, w+4}. Per step: 3 ds_read_b128 (remote
//   frags), 4 accumulator chains of depth 2 merged by v_add, pack, 1
//   ds_write_b128 (publish), next step's 2 LOCAL head MFMAs issued
//   PRE-barrier (absorb barrier-wait slack), 1 xp ring load (depth 8).
//   h->HBM: each wave stores its own u32x4, DELAYED 4 steps through an
//   8-slot register ring (pkv). With the clobber-free barrier, these
//   stores and the xp refills stay in flight across barriers -- no
//   per-step vmcnt drain (the R2-R6 stall).
// -------------------------------------------------------------------------
__global__ __launch_bounds__(256, 1)
void rec_kernel(const uint32_t* __restrict__ xp, const float* __restrict__ W1,
                uint32_t* __restrict__ hg) {
    const int g = blockIdx.x;
    const int w = threadIdx.x >> 6;   // 0..3
    const int l = threadIdx.x & 63;
    const int c = l & 15, u = l >> 4;

    __shared__ uint32_t hbuf[4][1024];   // 4-slot ring, 16 KB

    // h_0 = 0: zero slot 0
    for (int i = threadIdx.x; i < 1024; i += 256) hbuf[0][i] = 0;
    __syncthreads();

    // A-frags for m = w (e=0) and m = w+4 (e=1), phiB K-gather:
    //   waH[e][kt] elem j = W1h[16m+c][ 64*(j>>2) + 16kt + 4u + (j&3) ]
    f16x8 waH[2][4];
#pragma unroll
    for (int e = 0; e < 2; ++e) {
        const float* wr = W1 + (16 * (w + 4 * e) + c) * 256;  // cols 0..127
#pragma unroll
        for (int kt = 0; kt < 4; ++kt)
            waH[e][kt] = cvt_f16x8(*(const f32x4*)(wr + 16 * kt + 4 * u),
                                   *(const f32x4*)(wr + 64 + 16 * kt + 4 * u));
    }

    const uint32_t* xpl = xp + ((size_t)g * T_LEN) * 1024 + w * 256 + 4 * l;
    uint32_t*       hgp = hg + ((size_t)g * T_LEN) * 1024 + w * 256 + 4 * l;

    // xp prefetch ring, depth 8 (one b128 per step)
    u32x4 xr[8];
#pragma unroll
    for (int p = 0; p < 8; ++p)
        xr[p] = *(const u32x4*)(xpl + (size_t)p * 1024);

    // own B-frag bf[w] = {pk[w], pk[w+4]}; h_0 = 0
    f16x8 own;
    {
        const u32x4 z = {0, 0, 0, 0};
        own = __builtin_bit_cast(f16x8, z);
    }
    // loop invariant at entry of iter t: a0a/a1a = local heads for step t,
    // xf0/xf1 = unpacked xp of step t+1, own = h_t own-frag.
    f32x4 xf0, xf1, a0a, a1a;
    {
        U22 xq = __builtin_bit_cast(U22, xr[0]);
        xf0 = unpk4(xq.a);
        xf1 = unpk4(xq.b);
        a0a = MFMA32(waH[0][w], own, xf0);   // B=0 -> passes xf through
        a1a = MFMA32(waH[1][w], own, xf1);
        U22 xn = __builtin_bit_cast(U22, xr[1]);
        xf0 = unpk4(xn.a);
        xf1 = unpk4(xn.b);
    }
    u32x2 pkv[8][2];                         // 4-step-delayed store ring
    const f32x4 zf = { 0.f, 0.f, 0.f, 0.f };
    const int k1 = (w + 1) & 3, k2 = (w + 2) & 3, k3 = (w + 3) & 3;

#pragma unroll 1
    for (int t8 = 0; t8 < T_LEN; t8 += 8) {
#pragma unroll
        for (int p = 0; p < 8; ++p) {
            const int t = t8 + p;
            const uint32_t* rb = &hbuf[p & 3][0];   // slot t&3 = h_t
            // remote frags: issue at barrier+0, land under store/refill/MFMA
            u32x4 r1 = *(const u32x4*)&rb[k1 * 256 + 4 * l];
            u32x4 r2 = *(const u32x4*)&rb[k2 * 256 + 4 * l];
            u32x4 r3 = *(const u32x4*)&rb[k3 * 256 + 4 * l];
            // delayed h store: slot (t-4)&7 holds h_{t-3} -> hg[t-4]
            if (t >= 4) {
                U22 sq = { pkv[(p + 4) & 7][0], pkv[(p + 4) & 7][1] };
                *(u32x4*)(hgp + (size_t)(t - 4) * 1024) =
                    __builtin_bit_cast(u32x4, sq);
            }
            // ring refill for t+8 (clamped tail; dummies unused)
            int tn = t + 8; if (tn > T_LEN - 1) tn = T_LEN - 1;
            xr[p] = *(const u32x4*)(xpl + (size_t)tn * 1024);
            // 4 chains of depth 2 (heads a0a/a1a computed pre-barrier)
            f16x8 b1 = __builtin_bit_cast(f16x8, r1);
            f32x4 a0b = MFMA32(waH[0][k1], b1, zf);
            f32x4 a1b = MFMA32(waH[1][k1], b1, zf);
            f16x8 b2 = __builtin_bit_cast(f16x8, r2);
            a0a = MFMA32(waH[0][k2], b2, a0a);
            a1a = MFMA32(waH[1][k2], b2, a1a);
            f16x8 b3 = __builtin_bit_cast(f16x8, r3);
            a0b = MFMA32(waH[0][k3], b3, a0b);
            a1b = MFMA32(waH[1][k3], b3, a1b);
            // merge, pack h_{t+1}; own bf for t+1 is the register concat
            u32x2 p0 = relu_pk(a0a + a0b);
            u32x2 p1 = relu_pk(a1a + a1b);
            pkv[p & 7][0] = p0;              // read by store at iter t+4
            pkv[p & 7][1] = p1;
            U22 oq = { p0, p1 };
            own = __builtin_bit_cast(f16x8, oq);
            // publish own frag into slot (t+1)&3
            *(u32x4*)&hbuf[(p + 1) & 3][w * 256 + 4 * l] =
                __builtin_bit_cast(u32x4, oq);
            // next step's LOCAL heads: register-only, issued PRE-barrier to
            // absorb barrier-wait slack
            a0a = MFMA32(waH[0][w], own, xf0);
            a1a = MFMA32(waH[1][w], own, xf1);
            // unpack xp for step t+2 (pre-barrier tail filler)
            {
                U22 xq = __builtin_bit_cast(U22, xr[(p + 2) & 7]);
                xf0 = unpk4(xq.a);
                xf1 = unpk4(xq.b);
            }
            LDS_BARRIER();
        }
    }
    // epilogue: stores for the last 4 steps (h_{T-3}..h_T -> hg[T-4..T-1])
#pragma unroll
    for (int d = 0; d < 4; ++d) {
        U22 sq = { pkv[(T_LEN - 4 + d) & 7][0], pkv[(T_LEN - 4 + d) & 7][1] };
        *(u32x4*)(hgp + (size_t)(T_LEN - 4 + d) * 1024) =
            __builtin_bit_cast(u32x4, sq);
    }
}

// -------------------------------------------------------------------------
// Kernel 2: out[b,t,:] = relu(W2 . h_{t+1} + b2), K=32 MFMA: the stored
// q-th u32x4 of hg is verbatim a 16x16x32 B-frag (phiB with kt=q), so loads
// are 4 fully-coalesced u32x4 per t and MFMA count is halved vs K=16.
// A-frags of W2 use the same phiB two-load gather.
// Grid 2048 = g*512 + tc, block 64, 8 t per block.
// -------------------------------------------------------------------------
__global__ __launch_bounds__(64, 2)
void out_kernel(const uint32_t* __restrict__ hg, const float* __restrict__ W2,
                const float* __restrict__ b2, float* __restrict__ out) {
    const int bid = blockIdx.x;
    const int g   = bid >> 9;
    const int tc  = bid & 511;
    const int l   = threadIdx.x;
    const int c   = l & 15, u = l >> 4;

    // A[m][q] elem j = W2[16m+c][ 64*(j>>2) + 16q + 4u + (j&3) ]
    f16x8 wa[8][4];
#pragma unroll
    for (int m = 0; m < 8; ++m) {
        const float* wr = W2 + (16 * m + c) * 128;
#pragma unroll
        for (int q = 0; q < 4; ++q)
            wa[m][q] = cvt_f16x8(*(const f32x4*)(wr + 16 * q + 4 * u),
                                 *(const f32x4*)(wr + 64 + 16 * q + 4 * u));
    }
    f32x4 bi[8];
#pragma unroll
    for (int m = 0; m < 8; ++m) bi[m] = *(const f32x4*)(b2 + 16 * m + 4 * u);

    const int t0 = tc * 8;
    const uint32_t* hg0 = hg + ((size_t)g * T_LEN) * 1024 + 4 * l;
    float* op0 = out + (size_t)(16 * g + c) * T_LEN * NHID + 4 * u;
#pragma unroll 1
    for (int tt = 0; tt < 8; ++tt) {
        const int t = t0 + tt;
        const uint32_t* hp = hg0 + (size_t)t * 1024;
        f16x8 hb[4];
#pragma unroll
        for (int q = 0; q < 4; ++q)
            hb[q] = __builtin_bit_cast(f16x8, *(const u32x4*)(hp + q * 256));
        f32x4 acc[8];
#pragma unroll
        for (int m = 0; m < 8; ++m) {
            f32x4 a = bi[m];
#pragma unroll
            for (int q = 0; q < 4; ++q) a = MFMA32(wa[m][q], hb[q], a);
            acc[m] = relu4(a);
        }
        float* op = op0 + (size_t)t * NHID;
#pragma unroll
        for (int m = 0; m < 8; ++m) *(f32x4*)(op + 16 * m) = acc[m];
    }
}

// -------------------------------------------------------------------------
extern "C" void kernel_launch(void* const* d_in, const int* in_sizes, int n_in,
                              void* d_out, int out_size, void* d_ws, size_t ws_size,
                              hipStream_t stream) {
    const float* input = (const float*)d_in[0];  // (64, 4096, 128) f32
    const float* W1    = (const float*)d_in[1];  // (128, 256) f32
    const float* b1    = (const float*)d_in[2];  // (128,) f32
    const float* W2    = (const float*)d_in[3];  // (128, 128) f32
    const float* b2    = (const float*)d_in[4];  // (128,) f32
    float*    out = (float*)d_out;
    uint32_t* xpb = (uint32_t*)d_out;            // xp scratch (64 MiB, f16-
                                                 // packed) in d_out; fully
                                                 // consumed by rec before
                                                 // out_kernel overwrites
    uint32_t* hgb = (uint32_t*)d_ws;             // h stream: 64 MiB in d_ws

    xproj_kernel<<<1024, 64, 0, stream>>>(input, W1, b1, xpb);
    rec_kernel  <<<4,   256, 0, stream>>>(xpb, W1, hgb);
    out_kernel  <<<2048, 64, 0, stream>>>(hgb, W2, b2, out);
}